// Round 4
// baseline (171.697 us; speedup 1.0000x reference)
//
#include <hip/hip_runtime.h>
#include <math.h>

#define EPS 1e-5f
#define N0 1000
#define K1 500
#define K2 100
#define NE 32000
#define NB 64

__device__ __forceinline__ float bnr(float h, float sc, float sh) {
    float v = fmaf(h, sc, sh);
    return v > 0.f ? v : 0.f;
}

struct Args {
    const float *x; const int *ei; const float *ea;
    const float *w0, *b0, *g0, *be0;
    const float *w1, *b1, *g1, *be1;
    const float *w2a, *b2a, *g2a, *be2a;
    const float *w2b, *b2b, *g2b, *be2b;
    const float *w3a, *b3a, *w3b, *b3b;
    const float *p1_wrel, *p1_wroot, *p1_b, *p2_wrel, *p2_wroot, *p2_b;
    float *h0, *h1, *sums0, *sums1, *sums2a, *sums2b;
    float *t1, *sc1, *xp1, *h2a, *h2b, *t2, *sc2, *xp2;
    int *keep, *nidx, *nsrc, *ndst; float *new_ew;
    unsigned *bar, *gen;
    float *out;
};

// grid barrier: counter + monotonic generation, agent scope.
__device__ __forceinline__ void gsync(unsigned* bar, unsigned* gen) {
    __syncthreads();
    if (threadIdx.x == 0) {
        unsigned g = __hip_atomic_load(gen, __ATOMIC_RELAXED, __HIP_MEMORY_SCOPE_AGENT);
        unsigned a = __hip_atomic_fetch_add(bar, 1u, __ATOMIC_ACQ_REL, __HIP_MEMORY_SCOPE_AGENT);
        if (a == NB - 1) {
            __hip_atomic_store(bar, 0u, __ATOMIC_RELAXED, __HIP_MEMORY_SCOPE_AGENT);
            __hip_atomic_fetch_add(gen, 1u, __ATOMIC_ACQ_REL, __HIP_MEMORY_SCOPE_AGENT);
        } else {
            while (__hip_atomic_load(gen, __ATOMIC_ACQUIRE, __HIP_MEMORY_SCOPE_AGENT) == g) {
                __builtin_amdgcn_s_sleep(1);
            }
        }
        __threadfence();
    }
    __syncthreads();
}

// pre-kernel: zero BN accumulators + barrier state (ws is poisoned, not zeroed)
__global__ void k_pre(float* sums, unsigned* bar, unsigned* gen) {
    int t = threadIdx.x;
    for (int i = t; i < 912; i += 256) sums[i] = 0.f;
    if (t == 0) { *bar = 0u; *gen = 0u; }
}

__global__ __launch_bounds__(256) void k_mega(Args a) {
    union SMem {
        struct { float xs[64][65], wsm[128][65], rs[256], rq[256], sc[64], sh[64]; } mm;
        struct { float wsm[200][33], xs[10][33], sc[128], sh[128]; } l2b;
        struct { float acc[N0]; } sct;
        struct { float ss[N0], sc[200], sh[200]; } rk;
        struct { float sc[200], sh[200]; } bn;
        struct { float g[200], h3[128], o[2]; } fin;
    };
    __shared__ SMem sm;
    const int b = blockIdx.x, t = threadIdx.x;
    const int lane = t & 63, wv = t >> 6;

    // ---- Ph0: lin0 (blocks 0..7, 128 nodes each) ----
    if (b < 8) {
        int c = lane, ns = wv;
        int nb = b * 128;
        float wa = a.w0[c * 3], wb = a.w0[c * 3 + 1], wc = a.w0[c * 3 + 2], bb = a.b0[c];
        float s = 0.f, q = 0.f;
        for (int j = 0; j < 32; ++j) {
            int n = nb + ns + 4 * j;
            if (n < N0) {
                float h = fmaf(wa, a.x[n * 3], fmaf(wb, a.x[n * 3 + 1], fmaf(wc, a.x[n * 3 + 2], bb)));
                a.h0[n * 64 + c] = h;
                s += h; q += h * h;
            }
        }
        sm.mm.rs[t] = s; sm.mm.rq[t] = q;
        __syncthreads();
        if (ns == 0) {
            atomicAdd(&a.sums0[c],      sm.mm.rs[c] + sm.mm.rs[c + 64] + sm.mm.rs[c + 128] + sm.mm.rs[c + 192]);
            atomicAdd(&a.sums0[64 + c], sm.mm.rq[c] + sm.mm.rq[c + 64] + sm.mm.rq[c + 128] + sm.mm.rq[c + 192]);
        }
    }
    gsync(a.bar, a.gen);

    // ---- Ph1: lin1 (blocks 0..15, 64 nodes each) ----
    if (b < 16) {
        int nb = b * 64;
        if (t < 64) {
            float mu = a.sums0[t] * (1.f / N0);
            float var = a.sums0[64 + t] * (1.f / N0) - mu * mu;
            float s = a.g0[t] * rsqrtf(var + EPS);
            sm.mm.sc[t] = s; sm.mm.sh[t] = a.be0[t] - mu * s;
        }
        __syncthreads();
        for (int i = 0; i < 16; ++i) {
            int e = t + i * 256;
            int r = e >> 6, cc = e & 63;
            int n = nb + r;
            sm.mm.xs[r][cc] = (n < N0) ? bnr(a.h0[n * 64 + cc], sm.mm.sc[cc], sm.mm.sh[cc]) : 0.f;
            sm.mm.wsm[r][cc] = a.w1[e];
        }
        __syncthreads();
        int c = lane, ns = wv;
        float s = 0.f, q = 0.f;
        for (int j = 0; j < 16; ++j) {
            int ln = ns + 4 * j;
            int n = nb + ln;
            if (n < N0) {
                float acc = a.b1[c];
                #pragma unroll
                for (int k = 0; k < 64; ++k) acc = fmaf(sm.mm.xs[ln][k], sm.mm.wsm[c][k], acc);
                a.h1[n * 64 + c] = acc;
                s += acc; q += acc * acc;
            }
        }
        sm.mm.rs[t] = s; sm.mm.rq[t] = q;
        __syncthreads();
        if (ns == 0) {
            atomicAdd(&a.sums1[c],      sm.mm.rs[c] + sm.mm.rs[c + 64] + sm.mm.rs[c + 128] + sm.mm.rs[c + 192]);
            atomicAdd(&a.sums1[64 + c], sm.mm.rq[c] + sm.mm.rq[c + 64] + sm.mm.rq[c + 128] + sm.mm.rq[c + 192]);
        }
    }
    gsync(a.bar, a.gen);

    // ---- Ph2: score1 (wave-per-node, 16 nodes/block) ----
    if (b * 16 < N0) {
        if (t < 64) {
            float mu = a.sums1[t] * (1.f / N0);
            float var = a.sums1[64 + t] * (1.f / N0) - mu * mu;
            float sv = a.g1[t] * rsqrtf(var + EPS);
            sm.bn.sc[t] = sv; sm.bn.sh[t] = a.be1[t] - mu * sv;
        }
        __syncthreads();
        for (int it = 0; it < 4; ++it) {
            int n = b * 16 + it * 4 + wv;
            if (n < N0) {
                float v = bnr(a.h1[n * 64 + lane], sm.bn.sc[lane], sm.bn.sh[lane]);
                float dr = v * a.p1_wrel[lane], dt = v * a.p1_wroot[lane];
                #pragma unroll
                for (int m = 32; m >= 1; m >>= 1) {
                    dr += __shfl_xor(dr, m, 64);
                    dt += __shfl_xor(dt, m, 64);
                }
                if (lane == 0) { a.t1[n] = dr; a.sc1[n] = dt + a.p1_b[0]; }
            }
        }
    }
    gsync(a.bar, a.gen);

    // ---- Ph3: scatter1 (blocks 0..15, LDS-aggregated) ----
    if (b < 16) {
        for (int i = t; i < N0; i += 256) sm.sct.acc[i] = 0.f;
        __syncthreads();
        for (int e = b * 256 + t; e < NE; e += 16 * 256) {
            float w = a.ea[e];
            if (w != 0.f) atomicAdd(&sm.sct.acc[a.ei[NE + e]], w * a.t1[a.ei[e]]);
        }
        __syncthreads();
        for (int i = t; i < N0; i += 256) {
            float v = sm.sct.acc[i];
            if (v != 0.f) atomicAdd(&a.sc1[i], v);
        }
    }
    gsync(a.bar, a.gen);

    // ---- Ph4: rank1 + select (16 nodes/block) ----
    if (b * 16 < N0) {
        if (t < 64) {
            float mu = a.sums1[t] * (1.f / N0);
            float var = a.sums1[64 + t] * (1.f / N0) - mu * mu;
            float sv = a.g1[t] * rsqrtf(var + EPS);
            sm.rk.sc[t] = sv; sm.rk.sh[t] = a.be1[t] - mu * sv;
        }
        for (int i = t; i < N0; i += 256) sm.rk.ss[i] = a.sc1[i];
        __syncthreads();
        for (int it = 0; it < 4; ++it) {
            int n = b * 16 + it * 4 + wv;
            if (n < N0) {
                float s = sm.rk.ss[n];
                int r = 0;
                for (int m = lane; m < N0; m += 64) {
                    float smv = sm.rk.ss[m];
                    r += (smv > s) || (smv == s && m < n);
                }
                #pragma unroll
                for (int msk = 32; msk >= 1; msk >>= 1) r += __shfl_xor(r, msk, 64);
                if (lane == 0) { a.keep[n] = (r < K1) ? 1 : 0; a.nidx[n] = (r < K1) ? r : 0; }
                if (r < K1) {
                    float tn = tanhf(s);
                    a.xp1[r * 64 + lane] = bnr(a.h1[n * 64 + lane], sm.rk.sc[lane], sm.rk.sh[lane]) * tn;
                }
            }
        }
    }
    gsync(a.bar, a.gen);

    // ---- Ph5: lin2a (blocks 0..7) + edge remap (blocks 8..63) ----
    if (b < 8) {
        int nb = b * 64;
        for (int i = 0; i < 16; ++i) {
            int e = t + i * 256;
            int r = e >> 6, cc = e & 63;
            int n = nb + r;
            sm.mm.xs[r][cc] = (n < K1) ? a.xp1[n * 64 + cc] : 0.f;
        }
        for (int i = 0; i < 32; ++i) {
            int e = t + i * 256;
            sm.mm.wsm[e >> 6][e & 63] = a.w2a[e];
        }
        __syncthreads();
        int c = t & 127, ns = t >> 7;
        float s = 0.f, q = 0.f;
        for (int j = 0; j < 32; ++j) {
            int ln = ns + 2 * j;
            int n = nb + ln;
            if (n < K1) {
                float acc = a.b2a[c];
                #pragma unroll
                for (int k = 0; k < 64; ++k) acc = fmaf(sm.mm.xs[ln][k], sm.mm.wsm[c][k], acc);
                a.h2a[n * 128 + c] = acc;
                s += acc; q += acc * acc;
            }
        }
        sm.mm.rs[t] = s; sm.mm.rq[t] = q;
        __syncthreads();
        if (ns == 0) {
            atomicAdd(&a.sums2a[c],       sm.mm.rs[c] + sm.mm.rs[c + 128]);
            atomicAdd(&a.sums2a[128 + c], sm.mm.rq[c] + sm.mm.rq[c + 128]);
        }
    } else {
        for (int e = (b - 8) * 256 + t; e < NE; e += 56 * 256) {
            int s = a.ei[e], d = a.ei[NE + e];
            bool v = a.keep[s] && a.keep[d];
            a.nsrc[e] = v ? a.nidx[s] : 0;
            a.ndst[e] = v ? a.nidx[d] : 0;
            a.new_ew[e] = v ? a.ea[e] : 0.f;
        }
    }
    gsync(a.bar, a.gen);

    // ---- Ph6: lin2b (blocks 0..49, 10 nodes each, k-tiled) ----
    if (b < 50) {
        if (t < 128) {
            float mu = a.sums2a[t] * (1.f / K1);
            float var = a.sums2a[128 + t] * (1.f / K1) - mu * mu;
            float sv = a.g2a[t] * rsqrtf(var + EPS);
            sm.l2b.sc[t] = sv; sm.l2b.sh[t] = a.be2a[t] - mu * sv;
        }
        __syncthreads();
        int nb = b * 10;
        float acc[10];
        float bb = (t < 200) ? a.b2b[t] : 0.f;
        #pragma unroll
        for (int r = 0; r < 10; ++r) acc[r] = bb;
        for (int kt = 0; kt < 4; ++kt) {
            int k0 = kt * 32;
            __syncthreads();
            for (int e = t; e < 200 * 32; e += 256) {
                int r = e >> 5, k = e & 31;
                sm.l2b.wsm[r][k] = a.w2b[r * 128 + k0 + k];
            }
            for (int e = t; e < 10 * 32; e += 256) {
                int r = e >> 5, k = e & 31;
                sm.l2b.xs[r][k] = bnr(a.h2a[(nb + r) * 128 + k0 + k], sm.l2b.sc[k0 + k], sm.l2b.sh[k0 + k]);
            }
            __syncthreads();
            if (t < 200) {
                for (int k = 0; k < 32; ++k) {
                    float wv2 = sm.l2b.wsm[t][k];
                    #pragma unroll
                    for (int r = 0; r < 10; ++r) acc[r] = fmaf(sm.l2b.xs[r][k], wv2, acc[r]);
                }
            }
        }
        if (t < 200) {
            float s = 0.f, q = 0.f;
            #pragma unroll
            for (int r = 0; r < 10; ++r) {
                a.h2b[(nb + r) * 200 + t] = acc[r];
                s += acc[r]; q += acc[r] * acc[r];
            }
            atomicAdd(&a.sums2b[t], s);
            atomicAdd(&a.sums2b[200 + t], q);
        }
    }
    gsync(a.bar, a.gen);

    // ---- Ph7: score2 (wave-per-node, 8 nodes/block) ----
    if (b * 8 < K1) {
        if (t < 200) {
            float mu = a.sums2b[t] * (1.f / K1);
            float var = a.sums2b[200 + t] * (1.f / K1) - mu * mu;
            float sv = a.g2b[t] * rsqrtf(var + EPS);
            sm.bn.sc[t] = sv; sm.bn.sh[t] = a.be2b[t] - mu * sv;
        }
        __syncthreads();
        for (int it = 0; it < 2; ++it) {
            int n = b * 8 + it * 4 + wv;
            if (n < K1) {
                float dr = 0.f, dt = 0.f;
                #pragma unroll
                for (int j = 0; j < 4; ++j) {
                    int ch = lane + 64 * j;
                    if (ch < 200) {
                        float v = bnr(a.h2b[n * 200 + ch], sm.bn.sc[ch], sm.bn.sh[ch]);
                        dr = fmaf(v, a.p2_wrel[ch], dr);
                        dt = fmaf(v, a.p2_wroot[ch], dt);
                    }
                }
                #pragma unroll
                for (int m = 32; m >= 1; m >>= 1) {
                    dr += __shfl_xor(dr, m, 64);
                    dt += __shfl_xor(dt, m, 64);
                }
                if (lane == 0) { a.t2[n] = dr; a.sc2[n] = dt + a.p2_b[0]; }
            }
        }
    }
    gsync(a.bar, a.gen);

    // ---- Ph8: scatter2 (blocks 0..15) ----
    if (b < 16) {
        for (int i = t; i < K1; i += 256) sm.sct.acc[i] = 0.f;
        __syncthreads();
        for (int e = b * 256 + t; e < NE; e += 16 * 256) {
            float w = a.new_ew[e];
            if (w != 0.f) atomicAdd(&sm.sct.acc[a.ndst[e]], w * a.t2[a.nsrc[e]]);
        }
        __syncthreads();
        for (int i = t; i < K1; i += 256) {
            float v = sm.sct.acc[i];
            if (v != 0.f) atomicAdd(&a.sc2[i], v);
        }
    }
    gsync(a.bar, a.gen);

    // ---- Ph9: rank2 + select (8 nodes/block) ----
    if (b * 8 < K1) {
        if (t < 200) {
            float mu = a.sums2b[t] * (1.f / K1);
            float var = a.sums2b[200 + t] * (1.f / K1) - mu * mu;
            float sv = a.g2b[t] * rsqrtf(var + EPS);
            sm.rk.sc[t] = sv; sm.rk.sh[t] = a.be2b[t] - mu * sv;
        }
        for (int i = t; i < K1; i += 256) sm.rk.ss[i] = a.sc2[i];
        __syncthreads();
        for (int it = 0; it < 2; ++it) {
            int n = b * 8 + it * 4 + wv;
            if (n < K1) {
                float s = sm.rk.ss[n];
                int r = 0;
                for (int m = lane; m < K1; m += 64) {
                    float smv = sm.rk.ss[m];
                    r += (smv > s) || (smv == s && m < n);
                }
                #pragma unroll
                for (int msk = 32; msk >= 1; msk >>= 1) r += __shfl_xor(r, msk, 64);
                if (r < K2) {
                    float tn = tanhf(s);
                    #pragma unroll
                    for (int j = 0; j < 4; ++j) {
                        int ch = lane + 64 * j;
                        if (ch < 200)
                            a.xp2[r * 200 + ch] = bnr(a.h2b[n * 200 + ch], sm.rk.sc[ch], sm.rk.sh[ch]) * tn;
                    }
                }
            }
        }
    }
    gsync(a.bar, a.gen);

    // ---- Ph10: global max pool + mlp_third + log_softmax (block 0) ----
    if (b == 0) {
        if (t < 200) {
            float m0 = -1e30f, m1 = -1e30f, m2 = -1e30f, m3 = -1e30f;
            for (int n = 0; n < K2; n += 4) {
                m0 = fmaxf(m0, a.xp2[n * 200 + t]);
                m1 = fmaxf(m1, a.xp2[(n + 1) * 200 + t]);
                m2 = fmaxf(m2, a.xp2[(n + 2) * 200 + t]);
                m3 = fmaxf(m3, a.xp2[(n + 3) * 200 + t]);
            }
            sm.fin.g[t] = fmaxf(fmaxf(m0, m1), fmaxf(m2, m3));
        }
        __syncthreads();
        for (int i = 0; i < 32; ++i) {
            int r = wv + 4 * i;
            float p = 0.f;
            #pragma unroll
            for (int j = 0; j < 4; ++j) {
                int ch = lane + 64 * j;
                if (ch < 200) p = fmaf(a.w3a[r * 200 + ch], sm.fin.g[ch], p);
            }
            #pragma unroll
            for (int m = 32; m >= 1; m >>= 1) p += __shfl_xor(p, m, 64);
            if (lane == 0) sm.fin.h3[r] = fmaxf(p + a.b3a[r], 0.f);
        }
        __syncthreads();
        if (t < 128) {
            int ow = t >> 6;
            float p = a.w3b[ow * 128 + lane] * sm.fin.h3[lane]
                    + a.w3b[ow * 128 + 64 + lane] * sm.fin.h3[64 + lane];
            #pragma unroll
            for (int m = 32; m >= 1; m >>= 1) p += __shfl_xor(p, m, 64);
            if (lane == 0) sm.fin.o[ow] = fmaxf(p + a.b3b[ow], 0.f);
        }
        __syncthreads();
        if (t == 0) {
            float m = fmaxf(sm.fin.o[0], sm.fin.o[1]);
            float l = m + logf(expf(sm.fin.o[0] - m) + expf(sm.fin.o[1] - m));
            a.out[0] = sm.fin.o[0] - l;
            a.out[1] = sm.fin.o[1] - l;
        }
    }
}

extern "C" void kernel_launch(void* const* d_in, const int* in_sizes, int n_in,
                              void* d_out, int out_size, void* d_ws, size_t ws_size,
                              hipStream_t stream) {
    float* ws = (float*)d_ws;

    Args a;
    a.x    = (const float*)d_in[0];
    a.ei   = (const int*)d_in[1];
    a.ea   = (const float*)d_in[2];
    a.w0   = (const float*)d_in[3];  a.b0   = (const float*)d_in[4];
    a.g0   = (const float*)d_in[5];  a.be0  = (const float*)d_in[6];
    a.w1   = (const float*)d_in[7];  a.b1   = (const float*)d_in[8];
    a.g1   = (const float*)d_in[9];  a.be1  = (const float*)d_in[10];
    a.w2a  = (const float*)d_in[11]; a.b2a  = (const float*)d_in[12];
    a.g2a  = (const float*)d_in[13]; a.be2a = (const float*)d_in[14];
    a.w2b  = (const float*)d_in[15]; a.b2b  = (const float*)d_in[16];
    a.g2b  = (const float*)d_in[17]; a.be2b = (const float*)d_in[18];
    a.w3a  = (const float*)d_in[19]; a.b3a  = (const float*)d_in[20];
    a.w3b  = (const float*)d_in[21]; a.b3b  = (const float*)d_in[22];
    a.p1_wrel  = (const float*)d_in[23];
    a.p1_wroot = (const float*)d_in[24];
    a.p1_b     = (const float*)d_in[25];
    a.p2_wrel  = (const float*)d_in[26];
    a.p2_wroot = (const float*)d_in[27];
    a.p2_b     = (const float*)d_in[28];

    a.h0     = ws;                    // 64000
    a.h1     = ws + 64000;            // 64000
    a.sums0  = ws + 128000;           // 128
    a.sums1  = ws + 128128;           // 128
    a.sums2a = ws + 128256;           // 256
    a.sums2b = ws + 128512;           // 400  (sums block: 912 total @128000)
    a.t1     = ws + 129000;           // 1000
    a.sc1    = ws + 130000;           // 1000
    a.xp1    = ws + 131000;           // 32000
    a.h2a    = ws + 163000;           // 64000
    a.h2b    = ws + 227000;           // 100000
    a.t2     = ws + 327000;           // 500
    a.sc2    = ws + 327500;           // 500
    a.xp2    = ws + 328000;           // 20000
    a.keep   = (int*)(ws + 348000);   // 1000
    a.nidx   = (int*)(ws + 349000);   // 1000
    a.nsrc   = (int*)(ws + 350000);   // 32000
    a.ndst   = (int*)(ws + 382000);   // 32000
    a.new_ew = ws + 414000;           // 32000
    a.bar    = (unsigned*)(ws + 446080);
    a.gen    = (unsigned*)(ws + 446144);
    a.out    = (float*)d_out;

    k_pre<<<1, 256, 0, stream>>>(a.sums0, a.bar, a.gen);
    k_mega<<<NB, 256, 0, stream>>>(a);
}